// Round 18
// baseline (99.419 us; speedup 1.0000x reference)
//
#include <hip/hip_runtime.h>

typedef __attribute__((ext_vector_type(8)))  __bf16 bvec8;
typedef __attribute__((ext_vector_type(4)))  __bf16 bvec4;
typedef __attribute__((ext_vector_type(16))) float  fvec16;
typedef __attribute__((ext_vector_type(8)))  short  svec8;

// ---- pack W[l][j][k][i] fp32 -> Wp bf16 (R14 layout, proven) ----
// byte offset = t*32768 + it*2048 + h*1024 + lane*16 ; i = it*32+(lane&31),
// K = (2t+h)*16 + (lane>>5)*8 + e
__global__ __launch_bounds__(256) void pack_w(const float* __restrict__ W,
                                              __bf16* __restrict__ Wp) {
    int u = blockIdx.x * 256 + threadIdx.x;
    if (u >= 73728) return;                   // 36 t * 16 it * 2 h * 64 lanes
    int lane = u & 63;
    int h    = (u >> 6) & 1;
    int it   = (u >> 7) & 15;
    int t    = u >> 11;
    int i  = (it << 5) + (lane & 31);
    int K0 = ((2 * t + h) << 4) + ((lane >> 5) << 3);
    bvec8 o;
#pragma unroll
    for (int e = 0; e < 8; ++e) {
        int K  = K0 + e;
        int jk = K >> 7;
        int l  = K & 127;
        int j  = (jk * 11) >> 5;              // jk/3 for jk<9
        int k  = jk - 3 * j;
        o[e] = (__bf16)W[((l * 9 + j * 3 + k) << 9) + i];
    }
    *(bvec8*)&Wp[(size_t)u * 8] = o;
}

// ---- main: block = 2 batches x 512 i x 49 s, 1024 thr = 16 waves ----
// wave wd: wi = wd&7 (i-slice of 64, am2), bbw = wd>>3 (batch). sn2 per wave.
// acc[am2][sn2] = 64 AGPR; aW single-buffer [am][h] = 16 V, dist-1 prefetch.
// PER-WAVE K-ROTATION: off = (wd>>2 & 3)*2 — waves sharing a SIMD start at
// different jk groups, breaking the intra-SIMD pipe convoy.
// ys dedup (per batch, 78 rows x 128 l), 16B-unit swizzle u^=(row&15); row 77 zeros.
__global__ __launch_bounds__(1024, 4) void conv_mfma(
    const float* __restrict__ x, const __bf16* __restrict__ Wp,
    float* __restrict__ out)
{
    __shared__ __align__(16) char smem[65024];
    __bf16* xs = (__bf16*)smem;               // 12544 bf16 = 25088 B (per-batch stage)
    __bf16* ys = (__bf16*)(smem + 25088);     // 2 x 78 x 128 bf16 = 39936 B

    const int tid  = threadIdx.x;
    const int lane = tid & 63;
    const int l31  = lane & 31;
    const int ls5  = lane >> 5;
    const int wd   = tid >> 6;                // wave 0..15
    const int wi   = wd & 7;                  // i-slice [wi*64, wi*64+64)
    const int bbw  = wd >> 3;                 // batch within block
    const int b0   = blockIdx.x * 2;
    const int off  = ((wd >> 2) & 3) * 2;     // 0,2,4,6 — distinct per SIMD

    const float* xb  = x + (size_t)b0 * 12544;
    const char*  WpB = (const char*)Wp;
    const int wbase  = wi * 4096 + lane * 16; // wave's byte base within a 32 KB tile
    const int ysb    = bbw * 9984;            // wave's batch half of ys (elems)

    // ---- W prologue: wave's FIRST tile (off*4) into regs (lands during build) ----
    bvec8 aW[2][2];                           // [am][h], single buffer
#pragma unroll
    for (int am = 0; am < 2; ++am)
#pragma unroll
        for (int h = 0; h < 2; ++h)
            aW[am][h] = *(const bvec8*)(WpB + ((size_t)(off * 4) << 15)
                                        + wbase + am * 2048 + h * 1024);

    // ---- build: per batch sequentially (xs region reused) ----
    for (int bb = 0; bb < 2; ++bb) {
        for (int it = 0; it < 4; ++it) {
            int e4 = it * 1024 + tid;
            if (e4 < 3136) {
                const float4 v = ((const float4*)(xb + bb * 12544))[e4];
                bvec4 pk = { (__bf16)v.x, (__bf16)v.y, (__bf16)v.z, (__bf16)v.w };
                *(bvec4*)&xs[e4 * 4] = pk;
            }
        }
        __syncthreads();
        for (int it = 0; it < 2; ++it) {
            int up = it * 1024 + tid;
            if (up < 1248) {
                int row  = up >> 4;
                int useg = up & 15;
                int l0   = useg * 8;
                bvec8 ov;
                if (row == 77) {
                    ov = __builtin_bit_cast(bvec8, (svec8)0);
                } else if (row < 63) {
                    int t = row / 7, w = row - t * 7;
                    int tb = t + 5; if (tb >= 7) tb -= 7;
                    int cB = tb * 7 + w;
                    bool mA = (t >= 1) && (t <= 7);
                    int cA = mA ? (t - 1) * 7 + w : 0;
#pragma unroll
                    for (int d = 0; d < 8; ++d) {
                        float fa = mA ? (float)xs[(l0 + d) * 49 + cA] : 0.f;
                        float fb = (float)xs[(128 + l0 + d) * 49 + cB];
                        ov[d] = (__bf16)(fa + fb);
                    }
                } else if (row < 70) {
                    int w = row - 63;
#pragma unroll
                    for (int d = 0; d < 8; ++d) ov[d] = xs[(l0 + d) * 49 + w];
                } else {
                    int w = row - 70;
#pragma unroll
                    for (int d = 0; d < 8; ++d) ov[d] = xs[(l0 + d) * 49 + 7 + w];
                }
                *(bvec8*)&ys[((bb * 78 + row) << 7) + ((useg ^ (row & 15)) << 3)] = ov;
            }
        }
        __syncthreads();   // ys[bb] done; xs free for next batch (last: pre-K barrier)
    }

    // ---- per-lane column geometry: s = sn*32 + l31, both s-tiles per wave ----
    int nq[2], oo[2];
#pragma unroll
    for (int sn = 0; sn < 2; ++sn) {
        int s = sn * 32 + l31;
        int sc = (s < 49) ? s : 48;
        nq[sn] = sc / 7;
        oo[sn] = sc - nq[sn] * 7;
    }

    fvec16 acc[2][2];                          // [am][sn]
#pragma unroll
    for (int am = 0; am < 2; ++am)
#pragma unroll
        for (int sn = 0; sn < 2; ++sn)
#pragma unroll
            for (int r = 0; r < 16; ++r) acc[am][sn][r] = 0.f;

#define GEO(JK) {                                                             \
        int j_ = ((JK) * 11) >> 5; int k_ = (JK) - 3 * j_;                    \
        _Pragma("unroll")                                                     \
        for (int sn_ = 0; sn_ < 2; ++sn_) {                                   \
            int tw_ = oo[sn_] + k_ + 5; int w_ = tw_ >= 7 ? tw_ - 7 : tw_;    \
            int row_ = (nq[sn_] + j_) * 7 + w_;                               \
            if (nq[sn_] == 1 && j_ == 0) row_ = 63 + w_;                      \
            if (nq[sn_] == 0 && j_ == 2) row_ = 70 + w_;                      \
            if ((k_ == 0 && oo[sn_] == 0) || (k_ == 2 && oo[sn_] == 6))       \
                row_ = 77;                                                    \
            rowE[sn_] = ysb + ((row_) << 7); rx[sn_] = row_ & 15; } }

    // per K32 step: for h(2){ for sn(2){ 1 bf read; 2 MFMA } }; then prefetch TNEXT.
#define STEP(P, TNEXT, DOPF) {                                                \
        __builtin_amdgcn_s_setprio(1);                                        \
        _Pragma("unroll")                                                     \
        for (int h_ = 0; h_ < 2; ++h_)                                        \
        _Pragma("unroll")                                                     \
        for (int sn_ = 0; sn_ < 2; ++sn_) {                                   \
            int u_ = ((P) * 4 + h_ * 2 + ls5) ^ rx[sn_];                      \
            bvec8 bf_ = *(const bvec8*)&ys[rowE[sn_] + (u_ << 3)];            \
            _Pragma("unroll")                                                 \
            for (int am_ = 0; am_ < 2; ++am_)                                 \
                acc[am_][sn_] = __builtin_amdgcn_mfma_f32_32x32x16_bf16(      \
                    aW[am_][h_], bf_, acc[am_][sn_], 0, 0, 0);                \
        }                                                                     \
        __builtin_amdgcn_s_setprio(0);                                        \
        if (DOPF) {                                                           \
            const char* gp_ = WpB + ((size_t)(TNEXT) << 15) + wbase;          \
            _Pragma("unroll")                                                 \
            for (int am_ = 0; am_ < 2; ++am_)                                 \
            _Pragma("unroll")                                                 \
            for (int h_ = 0; h_ < 2; ++h_)                                    \
                aW[am_][h_] = *(const bvec8*)(gp_ + am_ * 2048 + h_ * 1024);  \
        } }

    // ---- K-loop: 9 rotated jk groups x 4 steps, barrier-free ----
    int rowE[2], rx[2];
    int jkr = off;
    for (int idx = 0; idx < 9; ++idx) {
        const int t0 = jkr * 4;
        const int jkn = (jkr + 1 == 9) ? 0 : jkr + 1;
        const bool last = (idx == 8);
        GEO(jkr);
        STEP(0, t0 + 1, true)
        STEP(1, t0 + 2, true)
        STEP(2, t0 + 3, true)
        STEP(3, jkn * 4, !last)
        jkr = jkn;
    }

#undef GEO
#undef STEP

    // ---- epilogue: direct stores. D row=(r&3)+8*(r>>2)+4*ls5 -> i ; col=l31 -> s ----
    const size_t ob = (size_t)(b0 + bbw) * 25088;
#pragma unroll
    for (int am = 0; am < 2; ++am) {
        const int i0 = wi * 64 + am * 32 + 4 * ls5;
#pragma unroll
        for (int sn = 0; sn < 2; ++sn) {
            if (sn == 1 && l31 >= 17) continue;   // s >= 49
            const int s = sn * 32 + l31;
#pragma unroll
            for (int r = 0; r < 16; ++r) {
                int i = i0 + (r & 3) + 8 * (r >> 2);
                out[ob + (size_t)i * 49 + s] = acc[am][sn][r];
            }
        }
    }
}

extern "C" void kernel_launch(void* const* d_in, const int* in_sizes, int n_in,
                              void* d_out, int out_size, void* d_ws, size_t ws_size,
                              hipStream_t stream) {
    const float* x = (const float*)d_in[0];   // (1024,256,7,7)
    const float* W = (const float*)d_in[1];   // (128,3,3,512)
    float* out = (float*)d_out;               // (1024,512,7,7)
    __bf16* Wp = (__bf16*)d_ws;               // 73728*8 bf16 = 1.18 MB
    (void)in_sizes; (void)n_in; (void)out_size; (void)ws_size;

    hipLaunchKernelGGL(pack_w, dim3(288), dim3(256), 0, stream, W, Wp);
    hipLaunchKernelGGL(conv_mfma, dim3(512), dim3(1024), 0, stream, x, Wp, out);
}

// Round 19
// 92.059 us; speedup vs baseline: 1.0799x; 1.0799x over previous
//
#include <hip/hip_runtime.h>

typedef __attribute__((ext_vector_type(8)))  __bf16 bvec8;
typedef __attribute__((ext_vector_type(4)))  __bf16 bvec4;
typedef __attribute__((ext_vector_type(16))) float  fvec16;
typedef __attribute__((ext_vector_type(8)))  short  svec8;

// ---- pack W[l][j][k][i] fp32 -> Wp bf16 (R14 layout, proven) ----
// byte offset = t*32768 + it*2048 + h*1024 + lane*16 ; i = it*32+(lane&31),
// K = (2t+h)*16 + (lane>>5)*8 + e
__global__ __launch_bounds__(256) void pack_w(const float* __restrict__ W,
                                              __bf16* __restrict__ Wp) {
    int u = blockIdx.x * 256 + threadIdx.x;
    if (u >= 73728) return;                   // 36 t * 16 it * 2 h * 64 lanes
    int lane = u & 63;
    int h    = (u >> 6) & 1;
    int it   = (u >> 7) & 15;
    int t    = u >> 11;
    int i  = (it << 5) + (lane & 31);
    int K0 = ((2 * t + h) << 4) + ((lane >> 5) << 3);
    bvec8 o;
#pragma unroll
    for (int e = 0; e < 8; ++e) {
        int K  = K0 + e;
        int jk = K >> 7;
        int l  = K & 127;
        int j  = (jk * 11) >> 5;              // jk/3 for jk<9
        int k  = jk - 3 * j;
        o[e] = (__bf16)W[((l * 9 + j * 3 + k) << 9) + i];
    }
    *(bvec8*)&Wp[(size_t)u * 8] = o;
}

// ---- main: block = 1 batch x 512 i x 49 s, 512 thr = 8 waves ----
// wave wd = wi (i-slice of 64, am2); sn2 per wave. acc[am2][sn2] = 64 AGPR.
// aW single-buffer [am][h] = 16 V, dist-1 prefetch (R17 structure).
// Per K32 step: 4 ds_read : 8 MFMA : 4 W b128 loads. ~60 V -> 4 waves/SIMD ->
// TWO independent blocks/CU: build/epilogue of one overlaps K-loop of the other.
// ys dedup (78 rows x 128 l), 16B-unit swizzle u^=(row&15); row 77 zeros.
__global__ __launch_bounds__(512, 4) void conv_mfma(
    const float* __restrict__ x, const __bf16* __restrict__ Wp,
    float* __restrict__ out)
{
    __shared__ __align__(16) char smem[45056];
    __bf16* xs = (__bf16*)smem;               // 12544 bf16 = 25088 B (stage)
    __bf16* ys = (__bf16*)(smem + 25088);     // 78 x 128 bf16 = 19968 B

    const int tid  = threadIdx.x;
    const int lane = tid & 63;
    const int l31  = lane & 31;
    const int ls5  = lane >> 5;
    const int wi   = tid >> 6;                // wave 0..7: i-slice [wi*64, wi*64+64)
    const int b    = blockIdx.x;

    const float* xb  = x + (size_t)b * 12544;
    const char*  WpB = (const char*)Wp;
    const int wbase  = wi * 4096 + lane * 16; // wave's byte base within a 32 KB tile

    // ---- W prologue: tile 0 into regs (lands during build) ----
    bvec8 aW[2][2];                           // [am][h], single buffer
#pragma unroll
    for (int am = 0; am < 2; ++am)
#pragma unroll
        for (int h = 0; h < 2; ++h)
            aW[am][h] = *(const bvec8*)(WpB + wbase + am * 2048 + h * 1024);

    // ---- build: stage x f32 -> xs bf16 (coalesced), then dedup ys ----
    for (int it = 0; it < 7; ++it) {
        int e4 = it * 512 + tid;
        if (e4 < 3136) {
            const float4 v = ((const float4*)xb)[e4];
            bvec4 pk = { (__bf16)v.x, (__bf16)v.y, (__bf16)v.z, (__bf16)v.w };
            *(bvec4*)&xs[e4 * 4] = pk;
        }
    }
    __syncthreads();
    for (int it = 0; it < 3; ++it) {
        int up = it * 512 + tid;
        if (up < 1248) {
            int row  = up >> 4;
            int useg = up & 15;
            int l0   = useg * 8;
            bvec8 ov;
            if (row == 77) {
                ov = __builtin_bit_cast(bvec8, (svec8)0);
            } else if (row < 63) {
                int t = row / 7, w = row - t * 7;
                int tb = t + 5; if (tb >= 7) tb -= 7;
                int cB = tb * 7 + w;
                bool mA = (t >= 1) && (t <= 7);
                int cA = mA ? (t - 1) * 7 + w : 0;
#pragma unroll
                for (int d = 0; d < 8; ++d) {
                    float fa = mA ? (float)xs[(l0 + d) * 49 + cA] : 0.f;
                    float fb = (float)xs[(128 + l0 + d) * 49 + cB];
                    ov[d] = (__bf16)(fa + fb);
                }
            } else if (row < 70) {
                int w = row - 63;
#pragma unroll
                for (int d = 0; d < 8; ++d) ov[d] = xs[(l0 + d) * 49 + w];
            } else {
                int w = row - 70;
#pragma unroll
                for (int d = 0; d < 8; ++d) ov[d] = xs[(l0 + d) * 49 + 7 + w];
            }
            *(bvec8*)&ys[(row << 7) + ((useg ^ (row & 15)) << 3)] = ov;
        }
    }

    // ---- per-lane column geometry: s = sn*32 + l31, both s-tiles per wave ----
    int nq[2], oo[2];
#pragma unroll
    for (int sn = 0; sn < 2; ++sn) {
        int s = sn * 32 + l31;
        int sc = (s < 49) ? s : 48;
        nq[sn] = sc / 7;
        oo[sn] = sc - nq[sn] * 7;
    }

    fvec16 acc[2][2];                          // [am][sn]
#pragma unroll
    for (int am = 0; am < 2; ++am)
#pragma unroll
        for (int sn = 0; sn < 2; ++sn)
#pragma unroll
            for (int r = 0; r < 16; ++r) acc[am][sn][r] = 0.f;

    __syncthreads();   // ys complete; no further barriers

#define GEO(JK) {                                                             \
        int j_ = ((JK) * 11) >> 5; int k_ = (JK) - 3 * j_;                    \
        _Pragma("unroll")                                                     \
        for (int sn_ = 0; sn_ < 2; ++sn_) {                                   \
            int tw_ = oo[sn_] + k_ + 5; int w_ = tw_ >= 7 ? tw_ - 7 : tw_;    \
            int row_ = (nq[sn_] + j_) * 7 + w_;                               \
            if (nq[sn_] == 1 && j_ == 0) row_ = 63 + w_;                      \
            if (nq[sn_] == 0 && j_ == 2) row_ = 70 + w_;                      \
            if ((k_ == 0 && oo[sn_] == 0) || (k_ == 2 && oo[sn_] == 6))       \
                row_ = 77;                                                    \
            rowE[sn_] = (row_) << 7; rx[sn_] = row_ & 15; } }

    // per K32 step: for h(2){ for sn(2){ 1 bf read; 2 MFMA } }; then prefetch TNEXT.
#define STEP(P, TNEXT, DOPF) {                                                \
        __builtin_amdgcn_s_setprio(1);                                        \
        _Pragma("unroll")                                                     \
        for (int h_ = 0; h_ < 2; ++h_)                                        \
        _Pragma("unroll")                                                     \
        for (int sn_ = 0; sn_ < 2; ++sn_) {                                   \
            int u_ = ((P) * 4 + h_ * 2 + ls5) ^ rx[sn_];                      \
            bvec8 bf_ = *(const bvec8*)&ys[rowE[sn_] + (u_ << 3)];            \
            _Pragma("unroll")                                                 \
            for (int am_ = 0; am_ < 2; ++am_)                                 \
                acc[am_][sn_] = __builtin_amdgcn_mfma_f32_32x32x16_bf16(      \
                    aW[am_][h_], bf_, acc[am_][sn_], 0, 0, 0);                \
        }                                                                     \
        __builtin_amdgcn_s_setprio(0);                                        \
        if (DOPF) {                                                           \
            const char* gp_ = WpB + ((size_t)(TNEXT) << 15) + wbase;          \
            _Pragma("unroll")                                                 \
            for (int am_ = 0; am_ < 2; ++am_)                                 \
            _Pragma("unroll")                                                 \
            for (int h_ = 0; h_ < 2; ++h_)                                    \
                aW[am_][h_] = *(const bvec8*)(gp_ + am_ * 2048 + h_ * 1024);  \
        } }

    // ---- K-loop: 9 jk x 4 steps, barrier-free, single-buffer dist-1 W ----
    int rowE[2], rx[2];
    for (int jk = 0; jk < 9; ++jk) {
        const int t0 = jk * 4;
        GEO(jk);
        STEP(0, t0 + 1, true)
        STEP(1, t0 + 2, true)
        STEP(2, t0 + 3, true)
        STEP(3, t0 + 4, (jk < 8))
    }

#undef GEO
#undef STEP

    // ---- epilogue: direct stores. D row=(r&3)+8*(r>>2)+4*ls5 -> i ; col=l31 -> s ----
    const size_t ob = (size_t)b * 25088;
#pragma unroll
    for (int am = 0; am < 2; ++am) {
        const int i0 = wi * 64 + am * 32 + 4 * ls5;
#pragma unroll
        for (int sn = 0; sn < 2; ++sn) {
            if (sn == 1 && l31 >= 17) continue;   // s >= 49
            const int s = sn * 32 + l31;
#pragma unroll
            for (int r = 0; r < 16; ++r) {
                int i = i0 + (r & 3) + 8 * (r >> 2);
                out[ob + (size_t)i * 49 + s] = acc[am][sn][r];
            }
        }
    }
}

extern "C" void kernel_launch(void* const* d_in, const int* in_sizes, int n_in,
                              void* d_out, int out_size, void* d_ws, size_t ws_size,
                              hipStream_t stream) {
    const float* x = (const float*)d_in[0];   // (1024,256,7,7)
    const float* W = (const float*)d_in[1];   // (128,3,3,512)
    float* out = (float*)d_out;               // (1024,512,7,7)
    __bf16* Wp = (__bf16*)d_ws;               // 73728*8 bf16 = 1.18 MB
    (void)in_sizes; (void)n_in; (void)out_size; (void)ws_size;

    hipLaunchKernelGGL(pack_w, dim3(288), dim3(256), 0, stream, W, Wp);
    hipLaunchKernelGGL(conv_mfma, dim3(1024), dim3(512), 0, stream, x, Wp, out);
}

// Round 20
// 89.962 us; speedup vs baseline: 1.1051x; 1.0233x over previous
//
#include <hip/hip_runtime.h>

typedef __attribute__((ext_vector_type(8)))  __bf16 bvec8;
typedef __attribute__((ext_vector_type(4)))  __bf16 bvec4;
typedef __attribute__((ext_vector_type(16))) float  fvec16;
typedef __attribute__((ext_vector_type(8)))  short  svec8;

// ---- pack W[l][j][k][i] fp32 -> Wp bf16 (R14 layout, proven) ----
// byte offset = t*32768 + it*2048 + h*1024 + lane*16 ; i = it*32+(lane&31),
// K = (2t+h)*16 + (lane>>5)*8 + e
__global__ __launch_bounds__(256) void pack_w(const float* __restrict__ W,
                                              __bf16* __restrict__ Wp) {
    int u = blockIdx.x * 256 + threadIdx.x;
    if (u >= 73728) return;                   // 36 t * 16 it * 2 h * 64 lanes
    int lane = u & 63;
    int h    = (u >> 6) & 1;
    int it   = (u >> 7) & 15;
    int t    = u >> 11;
    int i  = (it << 5) + (lane & 31);
    int K0 = ((2 * t + h) << 4) + ((lane >> 5) << 3);
    bvec8 o;
#pragma unroll
    for (int e = 0; e < 8; ++e) {
        int K  = K0 + e;
        int jk = K >> 7;
        int l  = K & 127;
        int j  = (jk * 11) >> 5;              // jk/3 for jk<9
        int k  = jk - 3 * j;
        o[e] = (__bf16)W[((l * 9 + j * 3 + k) << 9) + i];
    }
    *(bvec8*)&Wp[(size_t)u * 8] = o;
}

// ---- main: block = 1 batch x 512 i x 49 s, 512 thr = 8 waves ----
// wave wd = wi (i-slice of 64, am2); sn2 per wave. acc[am2][sn2] = 64 AGPR.
// W reg-dbuf DIST-2 (aE/aO, +16 V vs R19) to hide loaded-L2 latency.
// Per K32 step: 4 ds_read : 8 MFMA : 4 W b128 loads. ~76 V -> 4 waves/SIMD,
// 2 blocks/CU (LDS 45 KB): build/epilogue of one overlaps K-loop of the other.
// ys dedup (78 rows x 128 l), 16B-unit swizzle u^=(row&15); row 77 zeros.
__global__ __launch_bounds__(512, 4) void conv_mfma(
    const float* __restrict__ x, const __bf16* __restrict__ Wp,
    float* __restrict__ out)
{
    __shared__ __align__(16) char smem[45056];
    __bf16* xs = (__bf16*)smem;               // 12544 bf16 = 25088 B (stage)
    __bf16* ys = (__bf16*)(smem + 25088);     // 78 x 128 bf16 = 19968 B

    const int tid  = threadIdx.x;
    const int lane = tid & 63;
    const int l31  = lane & 31;
    const int ls5  = lane >> 5;
    const int wi   = tid >> 6;                // wave 0..7: i-slice [wi*64, wi*64+64)
    const int b    = blockIdx.x;

    const float* xb  = x + (size_t)b * 12544;
    const char*  WpB = (const char*)Wp;
    const int wbase  = wi * 4096 + lane * 16; // wave's byte base within a 32 KB tile

    // ---- W prologue: tiles 0,1 into dbuf regs (land during build) ----
    bvec8 aE[2][2], aO[2][2];                 // [am][h]
#pragma unroll
    for (int am = 0; am < 2; ++am)
#pragma unroll
        for (int h = 0; h < 2; ++h) {
            aE[am][h] = *(const bvec8*)(WpB + wbase + am * 2048 + h * 1024);
            aO[am][h] = *(const bvec8*)(WpB + 32768 + wbase + am * 2048 + h * 1024);
        }

    // ---- build: stage x f32 -> xs bf16 (coalesced), then dedup ys ----
    for (int it = 0; it < 7; ++it) {
        int e4 = it * 512 + tid;
        if (e4 < 3136) {
            const float4 v = ((const float4*)xb)[e4];
            bvec4 pk = { (__bf16)v.x, (__bf16)v.y, (__bf16)v.z, (__bf16)v.w };
            *(bvec4*)&xs[e4 * 4] = pk;
        }
    }
    __syncthreads();
    for (int it = 0; it < 3; ++it) {
        int up = it * 512 + tid;
        if (up < 1248) {
            int row  = up >> 4;
            int useg = up & 15;
            int l0   = useg * 8;
            bvec8 ov;
            if (row == 77) {
                ov = __builtin_bit_cast(bvec8, (svec8)0);
            } else if (row < 63) {
                int t = row / 7, w = row - t * 7;
                int tb = t + 5; if (tb >= 7) tb -= 7;
                int cB = tb * 7 + w;
                bool mA = (t >= 1) && (t <= 7);
                int cA = mA ? (t - 1) * 7 + w : 0;
#pragma unroll
                for (int d = 0; d < 8; ++d) {
                    float fa = mA ? (float)xs[(l0 + d) * 49 + cA] : 0.f;
                    float fb = (float)xs[(128 + l0 + d) * 49 + cB];
                    ov[d] = (__bf16)(fa + fb);
                }
            } else if (row < 70) {
                int w = row - 63;
#pragma unroll
                for (int d = 0; d < 8; ++d) ov[d] = xs[(l0 + d) * 49 + w];
            } else {
                int w = row - 70;
#pragma unroll
                for (int d = 0; d < 8; ++d) ov[d] = xs[(l0 + d) * 49 + 7 + w];
            }
            *(bvec8*)&ys[(row << 7) + ((useg ^ (row & 15)) << 3)] = ov;
        }
    }

    // ---- per-lane column geometry: s = sn*32 + l31, both s-tiles per wave ----
    int nq[2], oo[2];
#pragma unroll
    for (int sn = 0; sn < 2; ++sn) {
        int s = sn * 32 + l31;
        int sc = (s < 49) ? s : 48;
        nq[sn] = sc / 7;
        oo[sn] = sc - nq[sn] * 7;
    }

    fvec16 acc[2][2];                          // [am][sn]
#pragma unroll
    for (int am = 0; am < 2; ++am)
#pragma unroll
        for (int sn = 0; sn < 2; ++sn)
#pragma unroll
            for (int r = 0; r < 16; ++r) acc[am][sn][r] = 0.f;

    __syncthreads();   // ys complete; no further barriers

#define GEO(JK) {                                                             \
        int j_ = ((JK) * 11) >> 5; int k_ = (JK) - 3 * j_;                    \
        _Pragma("unroll")                                                     \
        for (int sn_ = 0; sn_ < 2; ++sn_) {                                   \
            int tw_ = oo[sn_] + k_ + 5; int w_ = tw_ >= 7 ? tw_ - 7 : tw_;    \
            int row_ = (nq[sn_] + j_) * 7 + w_;                               \
            if (nq[sn_] == 1 && j_ == 0) row_ = 63 + w_;                      \
            if (nq[sn_] == 0 && j_ == 2) row_ = 70 + w_;                      \
            if ((k_ == 0 && oo[sn_] == 0) || (k_ == 2 && oo[sn_] == 6))       \
                row_ = 77;                                                    \
            rowE[sn_] = (row_) << 7; rx[sn_] = row_ & 15; } }

    // per K32 step: for h(2){ for sn(2){ 1 bf read; 2 MFMA } }; prefetch tile t+2
    // into AW (the buffer just consumed) AFTER the MFMA cluster.
#define STEP(P, AW, TNEXT, DOPF) {                                            \
        _Pragma("unroll")                                                     \
        for (int h_ = 0; h_ < 2; ++h_)                                        \
        _Pragma("unroll")                                                     \
        for (int sn_ = 0; sn_ < 2; ++sn_) {                                   \
            int u_ = ((P) * 4 + h_ * 2 + ls5) ^ rx[sn_];                      \
            bvec8 bf_ = *(const bvec8*)&ys[rowE[sn_] + (u_ << 3)];            \
            __builtin_amdgcn_s_setprio(1);                                    \
            _Pragma("unroll")                                                 \
            for (int am_ = 0; am_ < 2; ++am_)                                 \
                acc[am_][sn_] = __builtin_amdgcn_mfma_f32_32x32x16_bf16(      \
                    AW[am_][h_], bf_, acc[am_][sn_], 0, 0, 0);                \
            __builtin_amdgcn_s_setprio(0);                                    \
        }                                                                     \
        if (DOPF) {                                                           \
            const char* gp_ = WpB + ((size_t)(TNEXT) << 15) + wbase;          \
            _Pragma("unroll")                                                 \
            for (int am_ = 0; am_ < 2; ++am_)                                 \
            _Pragma("unroll")                                                 \
            for (int h_ = 0; h_ < 2; ++h_)                                    \
                AW[am_][h_] = *(const bvec8*)(gp_ + am_ * 2048 + h_ * 1024);  \
        } }

    // ---- K-loop: 9 jk x 4 steps, barrier-free, dist-2 W dbuf ----
    int rowE[2], rx[2];
    for (int jk = 0; jk < 9; ++jk) {
        const int t0 = jk * 4;
        GEO(jk);
        STEP(0, aE, t0 + 2, true)
        STEP(1, aO, t0 + 3, true)
        STEP(2, aE, t0 + 4, (jk < 8))
        STEP(3, aO, t0 + 5, (jk < 8))
    }

#undef GEO
#undef STEP

    // ---- epilogue: direct stores. D row=(r&3)+8*(r>>2)+4*ls5 -> i ; col=l31 -> s ----
    const size_t ob = (size_t)b * 25088;
#pragma unroll
    for (int am = 0; am < 2; ++am) {
        const int i0 = wi * 64 + am * 32 + 4 * ls5;
#pragma unroll
        for (int sn = 0; sn < 2; ++sn) {
            if (sn == 1 && l31 >= 17) continue;   // s >= 49
            const int s = sn * 32 + l31;
#pragma unroll
            for (int r = 0; r < 16; ++r) {
                int i = i0 + (r & 3) + 8 * (r >> 2);
                out[ob + (size_t)i * 49 + s] = acc[am][sn][r];
            }
        }
    }
}

extern "C" void kernel_launch(void* const* d_in, const int* in_sizes, int n_in,
                              void* d_out, int out_size, void* d_ws, size_t ws_size,
                              hipStream_t stream) {
    const float* x = (const float*)d_in[0];   // (1024,256,7,7)
    const float* W = (const float*)d_in[1];   // (128,3,3,512)
    float* out = (float*)d_out;               // (1024,512,7,7)
    __bf16* Wp = (__bf16*)d_ws;               // 73728*8 bf16 = 1.18 MB
    (void)in_sizes; (void)n_in; (void)out_size; (void)ws_size;

    hipLaunchKernelGGL(pack_w, dim3(288), dim3(256), 0, stream, W, Wp);
    hipLaunchKernelGGL(conv_mfma, dim3(1024), dim3(512), 0, stream, x, Wp, out);
}